// Round 9
// baseline (22.866 us; speedup 1.0000x reference)
//
#include <hip/hip_runtime.h>
#include <hip/hip_fp16.h>

constexpr int Hc = 128, Wc = 128, Cc = 64;
constexpr int Qc = 512 * 512;

constexpr int PIX_PER_BLK = 16;   // conv: pixels per block
constexpr int CGRP = 16;          // conv: channel groups per block
constexpr int CPER = Cc / CGRP;   // 4 channels per group

constexpr int QBLK = 256;         // query blocks (1 per CU, LDS-capped)
constexpr int QPT = Qc / (QBLK * 256);   // 16 queries per thread
constexpr int TAB_BYTES = Hc * Wc * 8;   // 128 KB packed table

// ---------------------------------------------------------------------------
// Kernel 1: 3x3 conv (64 -> 3 ch) folded from unfold3+matmul, over 128x128.
// 1024 blocks; tid = cg*16 + px; LDS tree-reduce over 16 channel groups.
// Output: packed fp16 {s0,s1,s2,pad} = 8 B/pixel -> 128 KB table in d_ws.
// ---------------------------------------------------------------------------
__global__ __launch_bounds__(256) void conv3x3_S(const float* __restrict__ feat,
                                                 const float* __restrict__ wgt,
                                                 uint2* __restrict__ Sp) {
    __shared__ float ws[576 * 3];
    for (int i = threadIdx.x; i < 576 * 3; i += 256) ws[i] = wgt[i];

    __shared__ float part[CGRP][PIX_PER_BLK][3];   // [16][16][3]

    int px = threadIdx.x & (PIX_PER_BLK - 1);
    int cg = threadIdx.x >> 4;        // 0..15
    int pix = blockIdx.x * PIX_PER_BLK + px;
    int y = pix >> 7;
    int x = pix & 127;

    __syncthreads();                  // ws ready

    float a0 = 0.f, a1 = 0.f, a2 = 0.f;
    const int c0 = cg * CPER;
#pragma unroll
    for (int ci = 0; ci < CPER; ++ci) {
        int c = c0 + ci;
        const float* fc = feat + c * Hc * Wc;
        const float* wr = ws + c * 27;
#pragma unroll
        for (int di = 0; di < 3; ++di) {
            int yy = y + di - 1;
            bool yok = (unsigned)yy < (unsigned)Hc;
#pragma unroll
            for (int dj = 0; dj < 3; ++dj) {
                int xx = x + dj - 1;
                bool ok = yok && ((unsigned)xx < (unsigned)Wc);
                float v = ok ? fc[yy * Wc + xx] : 0.f;
                const float* wk = wr + (di * 3 + dj) * 3;
                a0 = fmaf(v, wk[0], a0);
                a1 = fmaf(v, wk[1], a1);
                a2 = fmaf(v, wk[2], a2);
            }
        }
    }

    part[cg][px][0] = a0;
    part[cg][px][1] = a1;
    part[cg][px][2] = a2;
    __syncthreads();

    // tree reduce over channel groups: 16 -> 8 -> 4 -> 2 -> 1
#pragma unroll
    for (int step = CGRP / 2; step > 0; step >>= 1) {
        if (cg < step) {
            part[cg][px][0] += part[cg + step][px][0];
            part[cg][px][1] += part[cg + step][px][1];
            part[cg][px][2] += part[cg + step][px][2];
        }
        __syncthreads();
    }

    if (cg == 0) {
        unsigned short u0 = __half_as_ushort(__float2half_rn(part[0][px][0]));
        unsigned short u1 = __half_as_ushort(__float2half_rn(part[0][px][1]));
        unsigned short u2 = __half_as_ushort(__float2half_rn(part[0][px][2]));
        uint2 o;
        o.x = (unsigned)u0 | ((unsigned)u1 << 16);
        o.y = (unsigned)u2;
        Sp[pix] = o;                                // 16 lanes, 128B coalesced
    }
}

// ---------------------------------------------------------------------------
// Kernel 2: stage the 128 KB fp16 table into dynamic LDS, then 16 queries per
// thread: 4 shifts -> nearest pixel -> ds_read_b64 gather -> linear tail +
// swapped-area blend. Gathers hit LDS banks instead of the L1/TA path.
// ---------------------------------------------------------------------------
__global__ __launch_bounds__(256) void liif_query(const float* __restrict__ coord,
                                                  const float* __restrict__ cell,
                                                  const float* __restrict__ wgt,
                                                  const float* __restrict__ bias,
                                                  const uint2* __restrict__ Sp,
                                                  float* __restrict__ out) {
    extern __shared__ uint2 tab[];   // 16384 entries = 128 KB

    // issue-early: preload this thread's 16 coord/cell pairs (static indices)
    const int qbase = blockIdx.x * (QPT * 256) + threadIdx.x;
    float2 cos_[QPT], ces_[QPT];
#pragma unroll
    for (int r = 0; r < QPT; ++r) {
        int q = qbase + r * 256;
        cos_[r] = *reinterpret_cast<const float2*>(coord + q * 2);
        ces_[r] = *reinterpret_cast<const float2*>(cell + q * 2);
    }

    // stage table: 8192 x uint4 across 256 threads = 32 coalesced 16B loads
    {
        const uint4* src = reinterpret_cast<const uint4*>(Sp);
        uint4* dst = reinterpret_cast<uint4*>(tab);
        for (int i = threadIdx.x; i < TAB_BYTES / 16; i += 256) dst[i] = src[i];
    }

    // tail weight rows 576..579 and bias (uniform)
    float wx0 = wgt[576 * 3 + 0], wx1 = wgt[576 * 3 + 1], wx2 = wgt[576 * 3 + 2];
    float wy0 = wgt[577 * 3 + 0], wy1 = wgt[577 * 3 + 1], wy2 = wgt[577 * 3 + 2];
    float wc0 = wgt[578 * 3 + 0], wc1 = wgt[578 * 3 + 1], wc2 = wgt[578 * 3 + 2];
    float wd0 = wgt[579 * 3 + 0], wd1 = wgt[579 * 3 + 1], wd2 = wgt[579 * 3 + 2];
    float b0 = bias[0], b1 = bias[1], b2 = bias[2];

    __syncthreads();                 // table ready

    // double-computed constants cast to fp32 (match numpy float64 scalar math)
    constexpr float SHN = (float)(-1.0 / 128.0 + 1e-6);
    constexpr float SHP = (float)( 1.0 / 128.0 + 1e-6);
    constexpr float CLO = (float)(-1.0 + 1e-6);
    constexpr float CHI = (float)( 1.0 - 1e-6);

#pragma unroll
    for (int r = 0; r < QPT; ++r) {
        int q = qbase + r * 256;
        float cox = cos_[r].x, coy = cos_[r].y;
        float rcx = ces_[r].x * 128.0f;
        float rcy = ces_[r].y * 128.0f;

        float pr[4][3];
        float area[4];
#pragma unroll
        for (int s = 0; s < 4; ++s) {
            // s=0:(-1,-1) s=1:(-1,+1) s=2:(+1,-1) s=3:(+1,+1)  (vx,vy)
            float sx = (s < 2) ? SHN : SHP;
            float sy = (s & 1) ? SHP : SHN;
            float cx_ = fminf(fmaxf(cox + sx, CLO), CHI);
            float cy_ = fminf(fmaxf(coy + sy, CLO), CHI);
            int ih = (int)floorf((cx_ + 1.0f) * 64.0f);
            ih = min(max(ih, 0), 127);
            int iw = (int)floorf((cy_ + 1.0f) * 64.0f);
            iw = min(max(iw, 0), 127);
            float qx = -1.0f + (float)(2 * ih + 1) * (1.0f / 128.0f);  // exact
            float qy = -1.0f + (float)(2 * iw + 1) * (1.0f / 128.0f);  // exact
            float relx = (cox - qx) * 128.0f;
            float rely = (coy - qy) * 128.0f;

            uint2 sv = tab[ih * 128 + iw];                 // ds_read_b64
            float2 s01 = __half22float2(*reinterpret_cast<const __half2*>(&sv.x));
            float s2 = __half2float(__ushort_as_half((unsigned short)(sv.y & 0xffffu)));

            pr[s][0] = s01.x + relx * wx0 + rely * wy0 + rcx * wc0 + rcy * wd0 + b0;
            pr[s][1] = s01.y + relx * wx1 + rely * wy1 + rcx * wc1 + rcy * wd1 + b1;
            pr[s][2] = s2    + relx * wx2 + rely * wy2 + rcx * wc2 + rcy * wd2 + b2;
            area[s] = fabsf(relx * rely) + 1e-9f;
        }

        float tot = area[0] + area[1] + area[2] + area[3];
        float inv = 1.0f / tot;
        // swapped-area weights: pred[i] * area[3-i]/tot
        float g0 = area[3] * inv, g1 = area[2] * inv, g2 = area[1] * inv, g3 = area[0] * inv;

        out[q * 3 + 0] = pr[0][0] * g0 + pr[1][0] * g1 + pr[2][0] * g2 + pr[3][0] * g3;
        out[q * 3 + 1] = pr[0][1] * g0 + pr[1][1] * g1 + pr[2][1] * g2 + pr[3][1] * g3;
        out[q * 3 + 2] = pr[0][2] * g0 + pr[1][2] * g1 + pr[2][2] * g2 + pr[3][2] * g3;
    }
}

extern "C" void kernel_launch(void* const* d_in, const int* in_sizes, int n_in,
                              void* d_out, int out_size, void* d_ws, size_t ws_size,
                              hipStream_t stream) {
    const float* feat  = (const float*)d_in[0];  // (1,64,128,128)
    const float* coord = (const float*)d_in[1];  // (1,Q,2)
    const float* cell  = (const float*)d_in[2];  // (1,Q,2)
    const float* wgt   = (const float*)d_in[3];  // (580,3)
    const float* bias  = (const float*)d_in[4];  // (3,)
    float* out = (float*)d_out;                  // (1,Q,3) fp32
    uint2* Sp  = (uint2*)d_ws;                   // packed fp16 table, 128 KB

    // allow 128 KB dynamic LDS for the query kernel (gfx950 has 160 KB/CU)
    static_assert(TAB_BYTES == 131072, "table size");
    hipFuncSetAttribute((const void*)liif_query,
                        hipFuncAttributeMaxDynamicSharedMemorySize, TAB_BYTES);

    conv3x3_S<<<(Hc * Wc) / PIX_PER_BLK, 256, 0, stream>>>(feat, wgt, Sp);
    liif_query<<<QBLK, 256, TAB_BYTES, stream>>>(coord, cell, wgt, bias, Sp, out);
}

// Round 10
// 15.982 us; speedup vs baseline: 1.4308x; 1.4308x over previous
//
#include <hip/hip_runtime.h>
#include <hip/hip_fp16.h>

constexpr int Hc = 128, Wc = 128, Cc = 64;
constexpr int Qc = 512 * 512;

constexpr int PIX_PER_BLK = 16;   // conv: pixels per block (1024 blocks)
constexpr int CGRP = 16;          // conv: channel groups per block
constexpr int CPER = Cc / CGRP;   // 4 channels per group

// ---------------------------------------------------------------------------
// Kernel 1: 3x3 conv (64 -> 3 ch) folded from unfold3+matmul, over 128x128.
// 1024 blocks; tid = cg*16 + px; LDS tree-reduce over 16 channel groups.
// Output: packed fp16 {s0,s1,s2,pad} = 8 B/pixel -> 128 KB table (halves
// gather bytes + doubles column-neighbor line sharing in kernel 2).
// ---------------------------------------------------------------------------
__global__ __launch_bounds__(256) void conv3x3_S(const float* __restrict__ feat,
                                                 const float* __restrict__ wgt,
                                                 uint2* __restrict__ Sp) {
    __shared__ float ws[576 * 3];
    for (int i = threadIdx.x; i < 576 * 3; i += 256) ws[i] = wgt[i];

    __shared__ float part[CGRP][PIX_PER_BLK][3];   // [16][16][3]

    int px = threadIdx.x & (PIX_PER_BLK - 1);
    int cg = threadIdx.x >> 4;        // 0..15
    int pix = blockIdx.x * PIX_PER_BLK + px;
    int y = pix >> 7;
    int x = pix & 127;

    __syncthreads();                  // ws ready

    float a0 = 0.f, a1 = 0.f, a2 = 0.f;
    const int c0 = cg * CPER;
#pragma unroll
    for (int ci = 0; ci < CPER; ++ci) {
        int c = c0 + ci;
        const float* fc = feat + c * Hc * Wc;
        const float* wr = ws + c * 27;
#pragma unroll
        for (int di = 0; di < 3; ++di) {
            int yy = y + di - 1;
            bool yok = (unsigned)yy < (unsigned)Hc;
#pragma unroll
            for (int dj = 0; dj < 3; ++dj) {
                int xx = x + dj - 1;
                bool ok = yok && ((unsigned)xx < (unsigned)Wc);
                float v = ok ? fc[yy * Wc + xx] : 0.f;
                const float* wk = wr + (di * 3 + dj) * 3;
                a0 = fmaf(v, wk[0], a0);
                a1 = fmaf(v, wk[1], a1);
                a2 = fmaf(v, wk[2], a2);
            }
        }
    }

    part[cg][px][0] = a0;
    part[cg][px][1] = a1;
    part[cg][px][2] = a2;
    __syncthreads();

    // tree reduce over channel groups: 16 -> 8 -> 4 -> 2 -> 1
#pragma unroll
    for (int step = CGRP / 2; step > 0; step >>= 1) {
        if (cg < step) {
            part[cg][px][0] += part[cg + step][px][0];
            part[cg][px][1] += part[cg + step][px][1];
            part[cg][px][2] += part[cg + step][px][2];
        }
        __syncthreads();
    }

    if (cg == 0) {
        unsigned short u0 = __half_as_ushort(__float2half_rn(part[0][px][0]));
        unsigned short u1 = __half_as_ushort(__float2half_rn(part[0][px][1]));
        unsigned short u2 = __half_as_ushort(__float2half_rn(part[0][px][2]));
        uint2 o;
        o.x = (unsigned)u0 | ((unsigned)u1 << 16);
        o.y = (unsigned)u2;
        Sp[pix] = o;                                // 16 lanes, 128B coalesced
    }
}

static __device__ __forceinline__ void unpack3(uint2 v, float& s0, float& s1, float& s2) {
    float2 p = __half22float2(*reinterpret_cast<const __half2*>(&v.x));
    s0 = p.x;
    s1 = p.y;
    s2 = __half2float(__ushort_as_half((unsigned short)(v.y & 0xffffu)));
}

// ---------------------------------------------------------------------------
// Kernel 2: 2 queries/thread, global-memory gathers (L2-hot 128 KB table).
// The 4 shifts are the cross product {ih_m,ih_p} x {iw_m,iw_p}: compute the
// index/rel algebra once per axis, gather the 2x2 pixel block (4 x 8 B,
// column pairs share a cache line), linear tail + swapped-area blend.
// ---------------------------------------------------------------------------
__global__ __launch_bounds__(256) void liif_query(const float* __restrict__ coord,
                                                  const float* __restrict__ cell,
                                                  const float* __restrict__ wgt,
                                                  const float* __restrict__ bias,
                                                  const uint2* __restrict__ Sp,
                                                  float* __restrict__ out) {
    int t = blockIdx.x * 256 + threadIdx.x;     // grid sized exactly Q/2
    int q0 = t * 2;

    float4 co = *reinterpret_cast<const float4*>(coord + q0 * 2);  // x0,y0,x1,y1
    float4 ce = *reinterpret_cast<const float4*>(cell + q0 * 2);

    // tail weight rows 576..579 and bias (uniform, scalar-cached)
    float wx0 = wgt[576 * 3 + 0], wx1 = wgt[576 * 3 + 1], wx2 = wgt[576 * 3 + 2];
    float wy0 = wgt[577 * 3 + 0], wy1 = wgt[577 * 3 + 1], wy2 = wgt[577 * 3 + 2];
    float wc0 = wgt[578 * 3 + 0], wc1 = wgt[578 * 3 + 1], wc2 = wgt[578 * 3 + 2];
    float wd0 = wgt[579 * 3 + 0], wd1 = wgt[579 * 3 + 1], wd2 = wgt[579 * 3 + 2];
    float b0 = bias[0], b1 = bias[1], b2 = bias[2];

    // double-computed constants cast to fp32 (match numpy float64 scalar math)
    constexpr float SHN = (float)(-1.0 / 128.0 + 1e-6);
    constexpr float SHP = (float)( 1.0 / 128.0 + 1e-6);
    constexpr float CLO = (float)(-1.0 + 1e-6);
    constexpr float CHI = (float)( 1.0 - 1e-6);

    float res[6];
#pragma unroll
    for (int k = 0; k < 2; ++k) {
        float cox = k ? co.z : co.x;
        float coy = k ? co.w : co.y;
        float rcx = (k ? ce.z : ce.x) * 128.0f;
        float rcy = (k ? ce.w : ce.y) * 128.0f;

        // ---- per-axis index + rel algebra (shifts are exactly +-0.5 px) ----
        float cxm = fminf(fmaxf(cox + SHN, CLO), CHI);
        float cxp = fminf(fmaxf(cox + SHP, CLO), CHI);
        int ihm = min(max((int)floorf((cxm + 1.0f) * 64.0f), 0), 127);
        int ihp = min(max((int)floorf((cxp + 1.0f) * 64.0f), 0), 127);
        float relxm = (cox - (-1.0f + (float)(2 * ihm + 1) * (1.0f / 128.0f))) * 128.0f;
        float relxp = (cox - (-1.0f + (float)(2 * ihp + 1) * (1.0f / 128.0f))) * 128.0f;

        float cym = fminf(fmaxf(coy + SHN, CLO), CHI);
        float cyp = fminf(fmaxf(coy + SHP, CLO), CHI);
        int iwm = min(max((int)floorf((cym + 1.0f) * 64.0f), 0), 127);
        int iwp = min(max((int)floorf((cyp + 1.0f) * 64.0f), 0), 127);
        float relym = (coy - (-1.0f + (float)(2 * iwm + 1) * (1.0f / 128.0f))) * 128.0f;
        float relyp = (coy - (-1.0f + (float)(2 * iwp + 1) * (1.0f / 128.0f))) * 128.0f;

        // ---- 2x2 gather (8 B each; column pair usually one cache line) ----
        const uint2* rm = Sp + ihm * 128;
        const uint2* rp = Sp + ihp * 128;
        uint2 v00 = rm[iwm], v01 = rm[iwp];
        uint2 v10 = rp[iwm], v11 = rp[iwp];

        float s[4][3];
        unpack3(v00, s[0][0], s[0][1], s[0][2]);   // (-1,-1)
        unpack3(v01, s[1][0], s[1][1], s[1][2]);   // (-1,+1)
        unpack3(v10, s[2][0], s[2][1], s[2][2]);   // (+1,-1)
        unpack3(v11, s[3][0], s[3][1], s[3][2]);   // (+1,+1)

        float rxs[4] = {relxm, relxm, relxp, relxp};
        float rys[4] = {relym, relyp, relym, relyp};

        float pr[4][3];
        float area[4];
#pragma unroll
        for (int sdx = 0; sdx < 4; ++sdx) {
            float relx = rxs[sdx], rely = rys[sdx];
            pr[sdx][0] = s[sdx][0] + relx * wx0 + rely * wy0 + rcx * wc0 + rcy * wd0 + b0;
            pr[sdx][1] = s[sdx][1] + relx * wx1 + rely * wy1 + rcx * wc1 + rcy * wd1 + b1;
            pr[sdx][2] = s[sdx][2] + relx * wx2 + rely * wy2 + rcx * wc2 + rcy * wd2 + b2;
            area[sdx] = fabsf(relx * rely) + 1e-9f;
        }

        float tot = area[0] + area[1] + area[2] + area[3];
        float inv = 1.0f / tot;
        // swapped-area weights: pred[i] * area[3-i]/tot
        float g0 = area[3] * inv, g1 = area[2] * inv, g2 = area[1] * inv, g3 = area[0] * inv;

        res[k * 3 + 0] = pr[0][0] * g0 + pr[1][0] * g1 + pr[2][0] * g2 + pr[3][0] * g3;
        res[k * 3 + 1] = pr[0][1] * g0 + pr[1][1] * g1 + pr[2][1] * g2 + pr[3][1] * g3;
        res[k * 3 + 2] = pr[0][2] * g0 + pr[1][2] * g1 + pr[2][2] * g2 + pr[3][2] * g3;
    }

    float2* op = reinterpret_cast<float2*>(out + q0 * 3);  // 8B-aligned (24B/thread)
    op[0] = make_float2(res[0], res[1]);
    op[1] = make_float2(res[2], res[3]);
    op[2] = make_float2(res[4], res[5]);
}

extern "C" void kernel_launch(void* const* d_in, const int* in_sizes, int n_in,
                              void* d_out, int out_size, void* d_ws, size_t ws_size,
                              hipStream_t stream) {
    const float* feat  = (const float*)d_in[0];  // (1,64,128,128)
    const float* coord = (const float*)d_in[1];  // (1,Q,2)
    const float* cell  = (const float*)d_in[2];  // (1,Q,2)
    const float* wgt   = (const float*)d_in[3];  // (580,3)
    const float* bias  = (const float*)d_in[4];  // (3,)
    float* out = (float*)d_out;                  // (1,Q,3) fp32
    uint2* Sp  = (uint2*)d_ws;                   // packed fp16 table, 128 KB

    conv3x3_S<<<(Hc * Wc) / PIX_PER_BLK, 256, 0, stream>>>(feat, wgt, Sp);
    liif_query<<<Qc / 512, 256, 0, stream>>>(coord, cell, wgt, bias, Sp, out);
}